// Round 2
// baseline (2025.812 us; speedup 1.0000x reference)
//
#include <hip/hip_runtime.h>
#include <math.h>

#define BB 8
#define NPTS 80000
#define KK 5
#define FF 20
#define GG 250           // blocks per batch -> 2000 blocks, exactly 5 tiles each
#define TILE 64
#define NTILES (NPTS / TILE)   // 1250, exact

// workspace layout (float offsets)
#define WS_CM 0          // cur means  [B,K,F] = 800
#define WS_CV 800        // cur var    = 800
#define WS_CP 1600       // cur pi     = 40
#define WS_A  1640       // A coef     = 40
#define WS_D  1680       // d coef     = 800
#define WS_E  2480       // e coef     = 800
#define WS_S0 3280       // 40
#define WS_S1 3320       // 800
#define WS_S2 4120       // 800
#define WS_TICKET 4920   // 1 uint (ticket for last-block M-step)

// ---- compute A/d/e from (means,var,pi) ----
__device__ __forceinline__ void make_coefs(const float* __restrict__ means,
                                           const float* __restrict__ var,
                                           const float* __restrict__ pi,
                                           float* __restrict__ A, float* __restrict__ D,
                                           float* __restrict__ E, int t) {
    if (t < BB * KK) {
        float sumlog = 0.f, summ2 = 0.f;
        for (int f = 0; f < FF; ++f) {
            float v = var[t * FF + f];
            float m = means[t * FF + f];
            float ic = 1.f / (v + 1e-6f);
            sumlog += logf(6.283185307179586f * v);
            summ2  += ic * m * m;
            D[t * FF + f] = ic * m;
            E[t * FF + f] = -0.5f * ic;
        }
        A[t] = logf(pi[t]) - 0.5f * sumlog - 0.5f * summ2;
    }
}

__global__ void prepare_kernel(const float* __restrict__ means, const float* __restrict__ var,
                               const float* __restrict__ pi, float* __restrict__ ws) {
    int t = threadIdx.x;
    float* S0 = ws + WS_S0; float* S1 = ws + WS_S1; float* S2 = ws + WS_S2;
    for (int i = t; i < BB * KK; i += blockDim.x) S0[i] = 0.f;
    for (int i = t; i < BB * KK * FF; i += blockDim.x) { S1[i] = 0.f; S2[i] = 0.f; }
    if (t == 0) ((unsigned*)(ws + WS_TICKET))[0] = 0u;
    make_coefs(means, var, pi, ws + WS_A, ws + WS_D, ws + WS_E, t);
}

// ---- E-step: per-wave cluster, per-lane point; accumulate (+fused M-step) or write outputs ----
template <bool WRITE_OUT>
__global__ __launch_bounds__(320) void estep_kernel(const float* __restrict__ data,
                                                    float* __restrict__ ws,
                                                    float* __restrict__ out_ll,
                                                    float* __restrict__ out_post,
                                                    float* __restrict__ om,
                                                    float* __restrict__ ov,
                                                    float* __restrict__ op,
                                                    int write_params) {
    __shared__ float xs[TILE][FF + 1];   // +1 pad: stride 21 -> conflict-free b32 reads
    __shared__ float lls[KK][TILE];
    __shared__ int   is_last;

    const int b    = blockIdx.x / GG;
    const int g    = blockIdx.x % GG;
    const int tid  = threadIdx.x;
    const int w    = __builtin_amdgcn_readfirstlane(tid >> 6);   // cluster k, wave-uniform
    const int lane = tid & 63;
    const int sp   = (tid * 4) / FF;     // staging LDS row
    const int sf   = (tid * 4) % FF;     // staging LDS col (multiple of 4)

    const float* A = ws + WS_A;
    const float* D = ws + WS_D;
    const float* E = ws + WS_E;

    const float Ak = A[b * KK + w];
    float dk[FF], ek[FF];
#pragma unroll
    for (int f = 0; f < FF; ++f) {
        dk[f] = D[(b * KK + w) * FF + f];
        ek[f] = E[(b * KK + w) * FF + f];
    }

    float s0 = 0.f, s1[FF], s2[FF];
    if (!WRITE_OUT) {
#pragma unroll
        for (int f = 0; f < FF; ++f) { s1[f] = 0.f; s2[f] = 0.f; }
    }

    const float* dbase = data + (size_t)b * NPTS * FF;

    // software prefetch: tile t's float4 is loaded one full iteration ahead
    float4 v = ((const float4*)(dbase + (size_t)g * TILE * FF))[tid];
    for (int t = g; t < NTILES; t += GG) {
        const int tn = t + GG;
        float4 vn = v;
        if (tn < NTILES) vn = ((const float4*)(dbase + (size_t)tn * TILE * FF))[tid];

        xs[sp][sf] = v.x; xs[sp][sf + 1] = v.y; xs[sp][sf + 2] = v.z; xs[sp][sf + 3] = v.w;
        __syncthreads();

        float x[FF];
        float z = Ak;
#pragma unroll
        for (int f = 0; f < FF; ++f) {
            x[f] = xs[lane][f];
            z += x[f] * fmaf(ek[f], x[f], dk[f]);
        }
        lls[w][lane] = z;
        __syncthreads();

        float l0 = lls[0][lane], l1 = lls[1][lane], l2 = lls[2][lane],
              l3 = lls[3][lane], l4 = lls[4][lane];
        float mx = fmaxf(fmaxf(fmaxf(l0, l1), fmaxf(l2, l3)), l4);
        float e0 = __expf(l0 - mx), e1 = __expf(l1 - mx), e2 = __expf(l2 - mx),
              e3 = __expf(l3 - mx), e4 = __expf(l4 - mx);
        float inv = 1.f / (e0 + e1 + e2 + e3 + e4);
        float ew  = (w == 0) ? e0 : (w == 1) ? e1 : (w == 2) ? e2 : (w == 3) ? e3 : e4;
        float post = ew * inv;

        if (WRITE_OUT) {
            size_t o = ((size_t)b * NPTS + (size_t)t * TILE + lane) * KK + w;
            out_ll[o]   = z;
            out_post[o] = post;
        } else {
            s0 += post;
#pragma unroll
            for (int f = 0; f < FF; ++f) {
                float px = post * x[f];
                s1[f] += px;
                s2[f] += px * x[f];
            }
        }
        v = vn;
    }

    if (!WRITE_OUT) {
        float* S0 = ws + WS_S0; float* S1 = ws + WS_S1; float* S2 = ws + WS_S2;
#pragma unroll
        for (int off = 32; off > 0; off >>= 1) {
            s0 += __shfl_down(s0, off);
#pragma unroll
            for (int f = 0; f < FF; ++f) {
                s1[f] += __shfl_down(s1[f], off);
                s2[f] += __shfl_down(s2[f], off);
            }
        }
        if (lane == 0) {
            atomicAdd(&S0[b * KK + w], s0);
#pragma unroll
            for (int f = 0; f < FF; ++f) {
                atomicAdd(&S1[(b * KK + w) * FF + f], s1[f]);
                atomicAdd(&S2[(b * KK + w) * FF + f], s2[f]);
            }
            __threadfence();   // order this wave's S-atomics before the ticket
        }
        __syncthreads();

        // -------- fused M-step: last block to finish does the parameter update --------
        unsigned* ticket = (unsigned*)(ws + WS_TICKET);
        if (tid == 0) {
            unsigned old = atomicAdd(ticket, 1u);
            is_last = (old == gridDim.x - 1) ? 1 : 0;
        }
        __syncthreads();
        if (is_last) {
            if (tid == 0) atomicExch(ticket, 0u);   // rearm for next dispatch
            float* cm = ws + WS_CM; float* cv = ws + WS_CV; float* cp = ws + WS_CP;
            // read S via atomic RMW(+0) so we observe other blocks' atomics at the
            // coherent point (plain loads could hit a stale line)
            for (int i = tid; i < BB * KK * FF; i += 320) {
                int bk = i / FF;
                float sz  = atomicAdd(&S0[bk], 0.f);
                float a1  = atomicAdd(&S1[i], 0.f);
                float a2  = atomicAdd(&S2[i], 0.f);
                float den = sz + 1e-7f;
                float m   = a1 / den;
                float var = (a2 - 2.f * m * a1 + m * m * sz) / den + 1e-6f;
                cm[i] = m; cv[i] = var;
                if (write_params) { om[i] = m; ov[i] = var; }
                S1[i] = 0.f; S2[i] = 0.f;   // re-zero for next dispatch
            }
            for (int i = tid; i < BB * KK; i += 320) {
                int bb = i / KK;
                float tot = 0.f;
                for (int j = 0; j < KK; ++j) tot += atomicAdd(&S0[bb * KK + j], 0.f);
                float pr = (atomicAdd(&S0[i], 0.f) / (float)NPTS) /
                           fmaxf(tot / (float)NPTS, 1e-12f);
                cp[i] = pr;
                if (write_params) op[i] = pr;
            }
            __syncthreads();   // all S0 reads done before zeroing
            for (int i = tid; i < BB * KK; i += 320) S0[i] = 0.f;
            __syncthreads();   // cm/cv/cp fully written before coef computation
            make_coefs(cm, cv, cp, ws + WS_A, ws + WS_D, ws + WS_E, tid);
        }
    }
}

extern "C" void kernel_launch(void* const* d_in, const int* in_sizes, int n_in,
                              void* d_out, int out_size, void* d_ws, size_t ws_size,
                              hipStream_t stream) {
    const float* data     = (const float*)d_in[0];
    const float* in_means = (const float*)d_in[1];
    const float* in_var   = (const float*)d_in[2];
    const float* in_pi    = (const float*)d_in[3];
    float* ws  = (float*)d_ws;
    float* out = (float*)d_out;

    float* out_ll   = out;
    float* out_post = out + (size_t)BB * NPTS * KK;
    float* om       = out + 2 * (size_t)BB * NPTS * KK;
    float* ov       = om + BB * KK * FF;
    float* op       = ov + BB * KK * FF;

    // iteration 0 coefs from inputs + zero accumulators/ticket
    prepare_kernel<<<1, 256, 0, stream>>>(in_means, in_var, in_pi, ws);

    for (int it = 0; it < 5; ++it) {
        estep_kernel<false><<<BB * GG, 320, 0, stream>>>(data, ws, nullptr, nullptr,
                                                         om, ov, op, (it == 4) ? 1 : 0);
    }
    // final E-step with post-loop params: write ll/post outputs
    estep_kernel<true><<<BB * GG, 320, 0, stream>>>(data, ws, out_ll, out_post,
                                                    nullptr, nullptr, nullptr, 0);
}

// Round 3
// 283.095 us; speedup vs baseline: 7.1560x; 7.1560x over previous
//
#include <hip/hip_runtime.h>
#include <math.h>

#define BB 8
#define NPTS 80000
#define KK 5
#define FF 20
#define GG 128           // blocks per batch -> 1024 blocks, ~10 tiles each
#define TILE 64
#define NTILES (NPTS / TILE)   // 1250, exact
#define PSTRIDE 48             // padded partial row: 20 s1 + 20 s2 + 1 s0 + pad

// workspace layout (float offsets) -- small params/coefs only
#define WS_CM 0          // cur means  [B,K,F] = 800
#define WS_CV 800        // cur var    = 800
#define WS_CP 1600       // cur pi     = 40
#define WS_A  1640       // A coef     = 40
#define WS_D  1680       // d coef     = 800
#define WS_E  2480       // e coef     = 800

// ---- compute A/d/e from (means,var,pi) ----
__device__ __forceinline__ void make_coefs(const float* __restrict__ means,
                                           const float* __restrict__ var,
                                           const float* __restrict__ pi,
                                           float* __restrict__ A, float* __restrict__ D,
                                           float* __restrict__ E, int t) {
    if (t < BB * KK) {
        float sumlog = 0.f, summ2 = 0.f;
        for (int f = 0; f < FF; ++f) {
            float v = var[t * FF + f];
            float m = means[t * FF + f];
            float ic = 1.f / (v + 1e-6f);
            sumlog += logf(6.283185307179586f * v);
            summ2  += ic * m * m;
            D[t * FF + f] = ic * m;
            E[t * FF + f] = -0.5f * ic;
        }
        A[t] = logf(pi[t]) - 0.5f * sumlog - 0.5f * summ2;
    }
}

__global__ void prepare_kernel(const float* __restrict__ means, const float* __restrict__ var,
                               const float* __restrict__ pi, float* __restrict__ ws) {
    make_coefs(means, var, pi, ws + WS_A, ws + WS_D, ws + WS_E, (int)threadIdx.x);
}

// ---- E-step: per-wave cluster, per-lane point; store per-block partials, no atomics ----
template <bool WRITE_OUT>
__global__ __launch_bounds__(320) void estep_kernel(const float* __restrict__ data,
                                                    const float* __restrict__ ws,
                                                    float* __restrict__ partials,
                                                    float* __restrict__ out_ll,
                                                    float* __restrict__ out_post) {
    __shared__ float xs[FF][TILE + 1];   // transposed: x[f]=xs[f][lane], (f+lane)%32 -> 2-way max
    __shared__ float lls[KK][TILE];

    const int b    = blockIdx.x / GG;
    const int g    = blockIdx.x % GG;
    const int tid  = threadIdx.x;
    const int w    = __builtin_amdgcn_readfirstlane(tid >> 6);   // cluster k, wave-uniform
    const int lane = tid & 63;
    const int sp   = (tid * 4) / FF;     // staging point index
    const int sf   = (tid * 4) % FF;     // staging feature base (multiple of 4)

    const float* A = ws + WS_A;
    const float* D = ws + WS_D;
    const float* E = ws + WS_E;

    const float Ak = A[b * KK + w];
    float dk[FF], ek[FF];                 // wave-uniform -> compiler puts these in SGPRs
#pragma unroll
    for (int f = 0; f < FF; ++f) {
        dk[f] = D[(b * KK + w) * FF + f];
        ek[f] = E[(b * KK + w) * FF + f];
    }

    float s0 = 0.f, s1[FF], s2[FF];
    if (!WRITE_OUT) {
#pragma unroll
        for (int f = 0; f < FF; ++f) { s1[f] = 0.f; s2[f] = 0.f; }
    }

    const float* dbase = data + (size_t)b * NPTS * FF;

    // software prefetch: tile t's float4 loaded one full iteration ahead
    float4 v = ((const float4*)(dbase + (size_t)g * TILE * FF))[tid];
    for (int t = g; t < NTILES; t += GG) {
        const int tn = t + GG;
        float4 vn = v;
        if (tn < NTILES) vn = ((const float4*)(dbase + (size_t)tn * TILE * FF))[tid];

        xs[sf][sp] = v.x; xs[sf + 1][sp] = v.y; xs[sf + 2][sp] = v.z; xs[sf + 3][sp] = v.w;
        __syncthreads();

        float x[FF];
        float z = Ak;
#pragma unroll
        for (int f = 0; f < FF; ++f) {
            x[f] = xs[f][lane];
            z += x[f] * fmaf(ek[f], x[f], dk[f]);
        }
        lls[w][lane] = z;
        __syncthreads();

        float l0 = lls[0][lane], l1 = lls[1][lane], l2 = lls[2][lane],
              l3 = lls[3][lane], l4 = lls[4][lane];
        float mx = fmaxf(fmaxf(fmaxf(l0, l1), fmaxf(l2, l3)), l4);
        float e0 = __expf(l0 - mx), e1 = __expf(l1 - mx), e2 = __expf(l2 - mx),
              e3 = __expf(l3 - mx), e4 = __expf(l4 - mx);
        float inv = 1.f / (e0 + e1 + e2 + e3 + e4);
        float ew  = (w == 0) ? e0 : (w == 1) ? e1 : (w == 2) ? e2 : (w == 3) ? e3 : e4;
        float post = ew * inv;

        if (WRITE_OUT) {
            size_t o = ((size_t)b * NPTS + (size_t)t * TILE + lane) * KK + w;
            out_ll[o]   = z;
            out_post[o] = post;
        } else {
            s0 += post;
#pragma unroll
            for (int f = 0; f < FF; ++f) {
                float px = post * x[f];
                s1[f] += px;
                s2[f] += px * x[f];
            }
        }
        v = vn;
    }

    if (!WRITE_OUT) {
#pragma unroll
        for (int off = 32; off > 0; off >>= 1) {
            s0 += __shfl_down(s0, off);
#pragma unroll
            for (int f = 0; f < FF; ++f) {
                s1[f] += __shfl_down(s1[f], off);
                s2[f] += __shfl_down(s2[f], off);
            }
        }
        if (lane == 0) {
            // unique row per (b,k,g): plain stores, zero contention
            float* row = partials + ((size_t)(b * KK + w) * GG + g) * PSTRIDE;
#pragma unroll
            for (int f = 0; f < FF; ++f) { row[f] = s1[f]; row[FF + f] = s2[f]; }
            row[2 * FF] = s0;
        }
    }
}

// ---- reduce partials + M-step + next-iteration coefs, one block per batch ----
__global__ __launch_bounds__(320) void update_kernel(const float* __restrict__ partials,
                                                     float* __restrict__ ws,
                                                     float* __restrict__ om,
                                                     float* __restrict__ ov,
                                                     float* __restrict__ op,
                                                     int write_params) {
    __shared__ float s0s[KK];
    const int b    = blockIdx.x;
    const int tid  = threadIdx.x;
    const int w    = tid >> 6;           // cluster k
    const int lane = tid & 63;
    const int bk   = b * KK + w;

    // lane l sums partial slot l over all g (coalesced 192B rows)
    float sv = 0.f;
    if (lane < PSTRIDE) {
        const float* base = partials + (size_t)bk * GG * PSTRIDE + lane;
        for (int gg = 0; gg < GG; ++gg) sv += base[(size_t)gg * PSTRIDE];
    }
    float s0  = __shfl(sv, 2 * FF);          // cluster size
    float den = s0 + 1e-7f;
    float m   = sv / den;                    // meaningful on lanes 0..19 (sv = S1[f])
    float s2f = __shfl(sv, FF + (lane % FF));// S2[f] for lane f
    float var = (s2f - 2.f * m * sv + m * m * s0) / den + 1e-6f;  // lanes 0..19

    float* cm = ws + WS_CM; float* cv = ws + WS_CV; float* cp = ws + WS_CP;
    if (lane < FF) {
        cm[bk * FF + lane] = m;
        cv[bk * FF + lane] = var;
        if (write_params) { om[bk * FF + lane] = m; ov[bk * FF + lane] = var; }
    }

    // pi: exchange cluster sizes across the 5 waves
    if (lane == 0) s0s[w] = s0;
    __syncthreads();
    float tot = s0s[0] + s0s[1] + s0s[2] + s0s[3] + s0s[4];
    float pr  = (s0 / (float)NPTS) / fmaxf(tot / (float)NPTS, 1e-12f);
    if (lane == 0) {
        cp[bk] = pr;
        if (write_params) op[bk] = pr;
    }

    // coefs for next E-step, computed in-register
    float ic = 1.f / (var + 1e-6f);
    if (lane < FF) {
        (ws + WS_D)[bk * FF + lane] = ic * m;
        (ws + WS_E)[bk * FF + lane] = -0.5f * ic;
    }
    float t1 = (lane < FF) ? logf(6.283185307179586f * var) : 0.f;
    float t2 = (lane < FF) ? ic * m * m : 0.f;
#pragma unroll
    for (int off = 1; off < 64; off <<= 1) {
        t1 += __shfl_xor(t1, off);
        t2 += __shfl_xor(t2, off);
    }
    if (lane == 0)
        (ws + WS_A)[bk] = logf(pr) - 0.5f * t1 - 0.5f * t2;
}

extern "C" void kernel_launch(void* const* d_in, const int* in_sizes, int n_in,
                              void* d_out, int out_size, void* d_ws, size_t ws_size,
                              hipStream_t stream) {
    const float* data     = (const float*)d_in[0];
    const float* in_means = (const float*)d_in[1];
    const float* in_var   = (const float*)d_in[2];
    const float* in_pi    = (const float*)d_in[3];
    float* ws  = (float*)d_ws;
    float* out = (float*)d_out;

    float* out_ll   = out;
    float* out_post = out + (size_t)BB * NPTS * KK;
    float* om       = out + 2 * (size_t)BB * NPTS * KK;
    float* ov       = om + BB * KK * FF;
    float* op       = ov + BB * KK * FF;

    // partial-sum buffer (983 KB) lives in the not-yet-needed ll output region;
    // the final E-step fully overwrites it.
    float* partials = out_ll;

    prepare_kernel<<<1, 64, 0, stream>>>(in_means, in_var, in_pi, ws);

    for (int it = 0; it < 5; ++it) {
        estep_kernel<false><<<BB * GG, 320, 0, stream>>>(data, ws, partials,
                                                         nullptr, nullptr);
        update_kernel<<<BB, 320, 0, stream>>>(partials, ws, om, ov, op,
                                              (it == 4) ? 1 : 0);
    }
    // final E-step with post-loop params: write ll/post outputs
    estep_kernel<true><<<BB * GG, 320, 0, stream>>>(data, ws, nullptr,
                                                    out_ll, out_post);
}